// Round 4
// baseline (49.901 us; speedup 1.0000x reference)
//
#include <hip/hip_runtime.h>
#include <math.h>

#define LOG_SQRT_2PI 0.9189385332046727f

typedef float f32x4 __attribute__((ext_vector_type(4)));

// ---------------------------------------------------------------------------
// Prior: one partial per block, no atomics, no pre-zeroed accumulator.
// ---------------------------------------------------------------------------
__global__ __launch_bounds__(256) void prior_partials(
        const float* __restrict__ pred,
        const float* __restrict__ sigma,
        float* __restrict__ ws, int B, int pb) {
    float s = 0.0f;
    for (int b = blockIdx.x * 256 + threadIdx.x; b < B; b += pb * 256) {
        const float* p  = pred  + (size_t)b * 7;
        const float* sg = sigma + (size_t)b * 7;
        float O2 = p[0], N2 = p[1], H2 = p[2], CO2 = p[3];
        float H2O = p[4], CH4 = p[5], NH3 = p[6];

        float H = 2.f*H2 + 2.f*H2O + 3.f*NH3 + 4.f*CH4;
        float C = CO2 + CH4;
        float O = 2.f*O2 + 2.f*CO2 + H2O;
        float N = 2.f*N2 + NH3;

        float mu0=0.f, mu1=0.f, mu2=0.f, mu3=0.f, mu4=0.f, mu5=0.f, mu6=0.f;

        bool condA = (H > 2.f*O + 4.f*C);
        if (condA) {
            if (3.f*N < H - 2.f*O - 4.f*C) {
                float D = H - N - 2.f*C;                 // branch A1
                mu2 = (H - 2.f*O - 4.f*C - 3.f*N) / D;
                mu4 = (2.f*O) / D;
                mu5 = (2.f*C) / D;
                mu6 = (2.f*N) / D;
            } else {
                float D = H + 2.f*C + 3.f*N + 4.f*O;    // branch A2
                mu1 = (3.f*N + 4.f*C + 2.f*O - H) / D;
                mu4 = (6.f*O) / D;
                mu5 = (6.f*C) / D;
                mu6 = (2.f*H - 8.f*C - 4.f*O) / D;
            }
        } else if (2.f*O > H + 4.f*C) {
            float D = H + 2.f*O + 2.f*N;                // branch B
            mu0 = (2.f*O - H - 4.f*C) / D;
            mu1 = (2.f*N) / D;
            mu3 = (4.f*C) / D;
            mu4 = (2.f*H) / D;
        } else if (fabsf(H + C + O + N - 1.0f) < 1e-3f) {
            float D1 = H + 2.f*O + 2.f*N;               // branch C
            float D2 = 2.f*H + 4.f*O + 4.f*N;
            mu1 = (2.f*N) / D1;
            mu3 = (2.f*O + 4.f*C - H) / D2;
            mu4 = (H + 2.f*O - 4.f*C) / D1;
            mu5 = (H - 2.f*O + 4.f*C) / D2;
        }

        float mu[7] = {mu0, mu1, mu2, mu3, mu4, mu5, mu6};
        #pragma unroll
        for (int i = 0; i < 7; ++i) {
            float d = p[i] - mu[i];
            float sgi = sg[i];
            s += LOG_SQRT_2PI + logf(sgi) + d * d / (2.0f * sgi * sgi);
        }
    }

    #pragma unroll
    for (int off = 32; off > 0; off >>= 1) s += __shfl_down(s, off, 64);
    __shared__ float wsum[4];
    int lane = threadIdx.x & 63, w = threadIdx.x >> 6;
    if (lane == 0) wsum[w] = s;
    __syncthreads();
    if (threadIdx.x == 0) ws[blockIdx.x] = wsum[0] + wsum[1] + wsum[2] + wsum[3];
}

// ---------------------------------------------------------------------------
// Loss, 4 rows per block: amortizes the reduce tail 4x, interleaved row
// loads give 8 outstanding float4 loads per unrolled step, and all 4 row
// sums + the prior fold share ONE shfl-reduce chain (latency overlapped).
// ---------------------------------------------------------------------------
template <int NITER>
__global__ __launch_bounds__(256) void loss_kernel4(
        const float* __restrict__ yReal,
        const float* __restrict__ ySim,
        const float* __restrict__ partials,
        float* __restrict__ out, int S, float c_mse, float c_prior, int pb) {
    int rb = blockIdx.x * 4;
    const f32x4* yr0 = (const f32x4*)(yReal + (size_t)(rb + 0) * S);
    const f32x4* yr1 = (const f32x4*)(yReal + (size_t)(rb + 1) * S);
    const f32x4* yr2 = (const f32x4*)(yReal + (size_t)(rb + 2) * S);
    const f32x4* yr3 = (const f32x4*)(yReal + (size_t)(rb + 3) * S);
    const f32x4* ys0 = (const f32x4*)(ySim  + (size_t)(rb + 0) * S);
    const f32x4* ys1 = (const f32x4*)(ySim  + (size_t)(rb + 1) * S);
    const f32x4* ys2 = (const f32x4*)(ySim  + (size_t)(rb + 2) * S);
    const f32x4* ys3 = (const f32x4*)(ySim  + (size_t)(rb + 3) * S);

    float u = (threadIdx.x < pb) ? partials[threadIdx.x] * c_prior : 0.0f;

    float s0 = 0.f, s1 = 0.f, s2 = 0.f, s3 = 0.f;
    #pragma unroll
    for (int k = 0; k < NITER; ++k) {
        int i = threadIdx.x + k * 256;
        f32x4 a0 = yr0[i], c0 = ys0[i];
        f32x4 a1 = yr1[i], c1 = ys1[i];
        f32x4 a2 = yr2[i], c2 = ys2[i];
        f32x4 a3 = yr3[i], c3 = ys3[i];
        f32x4 d0 = a0 - c0, d1 = a1 - c1, d2 = a2 - c2, d3 = a3 - c3;
        s0 += d0.x*d0.x + d0.y*d0.y + d0.z*d0.z + d0.w*d0.w;
        s1 += d1.x*d1.x + d1.y*d1.y + d1.z*d1.z + d1.w*d1.w;
        s2 += d2.x*d2.x + d2.y*d2.y + d2.z*d2.z + d2.w*d2.w;
        s3 += d3.x*d3.x + d3.y*d3.y + d3.z*d3.z + d3.w*d3.w;
    }

    // one shfl chain reduces all 5 values (latency shared)
    #pragma unroll
    for (int off = 32; off > 0; off >>= 1) {
        s0 += __shfl_down(s0, off, 64);
        s1 += __shfl_down(s1, off, 64);
        s2 += __shfl_down(s2, off, 64);
        s3 += __shfl_down(s3, off, 64);
        u  += __shfl_down(u,  off, 64);
    }
    __shared__ float wsum[4][5];
    int lane = threadIdx.x & 63, w = threadIdx.x >> 6;
    if (lane == 0) {
        wsum[w][0] = s0; wsum[w][1] = s1; wsum[w][2] = s2;
        wsum[w][3] = s3; wsum[w][4] = u;
    }
    __syncthreads();
    if (threadIdx.x < 4) {
        float t  = wsum[0][threadIdx.x] + wsum[1][threadIdx.x]
                 + wsum[2][threadIdx.x] + wsum[3][threadIdx.x];
        float up = wsum[0][4] + wsum[1][4] + wsum[2][4] + wsum[3][4];
        out[rb + threadIdx.x] = t * c_mse + up;
    }
}

// generic fallback (runtime trip count, one row per block)
__global__ __launch_bounds__(256) void loss_kernel_g(
        const float* __restrict__ yReal,
        const float* __restrict__ ySim,
        const float* __restrict__ partials,
        float* __restrict__ out, int S, float c_mse, float c_prior, int pb) {
    int b = blockIdx.x;
    const float* yr = yReal + (size_t)b * S;
    const float* ys = ySim  + (size_t)b * S;

    float u = (threadIdx.x < pb) ? partials[threadIdx.x] * c_prior : 0.0f;

    float s = 0.0f;
    int n4 = S >> 2;
    const f32x4* yr4 = (const f32x4*)yr;
    const f32x4* ys4 = (const f32x4*)ys;
    for (int i = threadIdx.x; i < n4; i += 256) {
        f32x4 a = yr4[i];
        f32x4 c = ys4[i];
        f32x4 d = a - c;
        s += d.x*d.x + d.y*d.y + d.z*d.z + d.w*d.w;
    }
    for (int i = (n4 << 2) + threadIdx.x; i < S; i += 256) {
        float d = yr[i] - ys[i];
        s += d * d;
    }
    u += s * c_mse;

    #pragma unroll
    for (int off = 32; off > 0; off >>= 1) u += __shfl_down(u, off, 64);
    __shared__ float wsum[4];
    int lane = threadIdx.x & 63, w = threadIdx.x >> 6;
    if (lane == 0) wsum[w] = u;
    __syncthreads();
    if (threadIdx.x == 0) out[b] = wsum[0] + wsum[1] + wsum[2] + wsum[3];
}

extern "C" void kernel_launch(void* const* d_in, const int* in_sizes, int n_in,
                              void* d_out, int out_size, void* d_ws, size_t ws_size,
                              hipStream_t stream) {
    const float* pred  = (const float*)d_in[0];
    const float* sigma = (const float*)d_in[1];
    const float* yReal = (const float*)d_in[2];
    const float* ySim  = (const float*)d_in[3];
    float* out = (float*)d_out;
    float* ws  = (float*)d_ws;

    int B = in_sizes[0] / 7;
    int S = in_sizes[2] / B;

    int pb = (B + 255) / 256;
    if (pb > 256) pb = 256;   // loss folds partials via tid<pb, so cap at 256

    prior_partials<<<pb, 256, 0, stream>>>(pred, sigma, ws, B, pb);

    float c_mse   = 50.0f / (float)S;   // (1/S)*(1/(2*0.1^2))
    float c_prior = 1.0f / (float)B;

    if ((B & 3) == 0 && S == 4096) {
        loss_kernel4<4><<<B / 4, 256, 0, stream>>>(yReal, ySim, ws, out, S, c_mse, c_prior, pb);
    } else if ((B & 3) == 0 && S == 2048) {
        loss_kernel4<2><<<B / 4, 256, 0, stream>>>(yReal, ySim, ws, out, S, c_mse, c_prior, pb);
    } else {
        loss_kernel_g<<<B, 256, 0, stream>>>(yReal, ySim, ws, out, S, c_mse, c_prior, pb);
    }
}